// Round 2
// baseline (9913.113 us; speedup 1.0000x reference)
//
#include <hip/hip_runtime.h>

#define HID 128
#define OUTD 64
#define N_SOTU 500000
#define N_TAXON 200000
#define E_TT 200000
#define E_TS 1000000
#define E_LBL 500000
#define HALF_S 250000

typedef short s16x8 __attribute__((ext_vector_type(8)));   // 8 bf16 (4 VGPRs), guide-verified MFMA frag type
typedef float f32x4 __attribute__((ext_vector_type(4)));

__device__ __forceinline__ unsigned short f2bf(float f) {  // f32 -> bf16 bits, RNE
    unsigned u = __builtin_bit_cast(unsigned, f);
    u += 0x7FFFu + ((u >> 16) & 1u);
    return (unsigned short)(u >> 16);
}
__device__ __forceinline__ float bf2f(unsigned short h) {
    unsigned u = ((unsigned)h) << 16;
    return __builtin_bit_cast(float, u);
}

// ---------------- degree count ----------------
__global__ void deg_kernel(const int* __restrict__ dst, int n, float* __restrict__ deg) {
    int e = blockIdx.x * 256 + threadIdx.x;
    if (e < n) unsafeAtomicAdd(&deg[dst[e]], 1.0f);
}

// ---------------- scatter-add rows into fp32 agg (dst range [lo,hi), agg indexed dst-lo) ----------
// 16 threads per edge, 8 features each. Source is f32 (xf, optionally via xids) or bf16 (xb).
__global__ void scatter_kernel(const float* __restrict__ xf, const unsigned short* __restrict__ xb,
                               const int* __restrict__ xids,
                               const int* __restrict__ src, const int* __restrict__ dst,
                               int n_edges, int lo, int hi, float* __restrict__ agg) {
    int t = blockIdx.x * 256 + threadIdx.x;
    int e = t >> 4;
    if (e >= n_edges) return;
    int d = dst[e];
    if (d < lo || d >= hi) return;
    int part = t & 15;
    int s = src[e];
    if (xids) s = xids[s];
    float v[8];
    if (xf) {
        float4 v0 = *(const float4*)(xf + (size_t)s * HID + part * 8);
        float4 v1 = *(const float4*)(xf + (size_t)s * HID + part * 8 + 4);
        v[0] = v0.x; v[1] = v0.y; v[2] = v0.z; v[3] = v0.w;
        v[4] = v1.x; v[5] = v1.y; v[6] = v1.z; v[7] = v1.w;
    } else {
        s16x8 b = *(const s16x8*)(xb + (size_t)s * HID + part * 8);
#pragma unroll
        for (int i = 0; i < 8; i++) v[i] = bf2f((unsigned short)b[i]);
    }
    float* ar = agg + (size_t)(d - lo) * HID + part * 8;
#pragma unroll
    for (int i = 0; i < 8; i++) unsafeAtomicAdd(ar + i, v[i]);
}

// ---------------- fused SAGE layer: out = relu( (agg/deg)@wl + x@wr + bl ) ----------------
// MFMA 16x16x32 bf16, K=256 (concat [aggn | x]), N=128. f32 weights -> bf16 LDS (transposed,
// XOR-granule-swizzled against the 512B stride).
__device__ __forceinline__ int wt_idx(int n, int k) {
    return n * 256 + ((((k >> 3) ^ n) & 31) << 3) + (k & 7);
}

__global__ __launch_bounds__(256) void sage_kernel(
    int n_rows, int row0,
    const float* __restrict__ agg,   // local rows [0, n_rows)
    const float* __restrict__ deg,   // pre-offset by row0
    const float* __restrict__ xf, const unsigned short* __restrict__ xb,  // one non-null
    const int* __restrict__ xids,    // pre-offset by row0; if null, xrow = row0 + local
    const float* __restrict__ wl, const float* __restrict__ wr,
    const float* __restrict__ bl,
    unsigned short* __restrict__ out)  // pre-offset by row0*HID
{
    __shared__ __align__(16) unsigned short WT[128 * 256];  // 64 KB: WT[n][k], k<128 wl, k>=128 wr
    for (int idx = threadIdx.x; idx < 128 * 128; idx += 256) {
        int n = idx & 127, k = idx >> 7;
        WT[wt_idx(n, k)]       = f2bf(wl[idx]);   // wl[k][n]
        WT[wt_idx(n, k + 128)] = f2bf(wr[idx]);   // wr[k][n]
    }
    __syncthreads();
    const int lane = threadIdx.x & 63, wid = threadIdx.x >> 6;
    const int l16 = lane & 15, q = lane >> 4;
    const int n_tiles = n_rows >> 4;
    const int stride = gridDim.x * 4;
    for (int tile = blockIdx.x * 4 + wid; tile < n_tiles; tile += stride) {
        const int base = tile << 4;
        const int lrow = base + l16;     // A-operand row (local) this lane feeds
        const float idg = 1.0f / fmaxf(deg[lrow], 1.0f);
        const size_t xrow = xids ? (size_t)xids[lrow] : (size_t)(row0 + lrow);
        f32x4 acc[8] = {};
        // K = 0..127 : normalized aggregation (fp32 -> bf16 on the fly)
#pragma unroll
        for (int ks = 0; ks < 4; ks++) {
            const float* ap = agg + (size_t)lrow * HID + ks * 32 + q * 8;
            float4 v0 = *(const float4*)ap;
            float4 v1 = *(const float4*)(ap + 4);
            s16x8 a;
            a[0] = (short)f2bf(v0.x * idg); a[1] = (short)f2bf(v0.y * idg);
            a[2] = (short)f2bf(v0.z * idg); a[3] = (short)f2bf(v0.w * idg);
            a[4] = (short)f2bf(v1.x * idg); a[5] = (short)f2bf(v1.y * idg);
            a[6] = (short)f2bf(v1.z * idg); a[7] = (short)f2bf(v1.w * idg);
            const int kb = ks * 32 + q * 8;
#pragma unroll
            for (int nt = 0; nt < 8; nt++) {
                s16x8 b = *(const s16x8*)&WT[wt_idx(nt * 16 + l16, kb)];
                acc[nt] = __builtin_amdgcn_mfma_f32_16x16x32_bf16(a, b, acc[nt], 0, 0, 0);
            }
        }
        // K = 128..255 : x_dst
#pragma unroll
        for (int ks = 0; ks < 4; ks++) {
            s16x8 a;
            if (xf) {
                const float* xp = xf + xrow * HID + ks * 32 + q * 8;
                float4 v0 = *(const float4*)xp;
                float4 v1 = *(const float4*)(xp + 4);
                a[0] = (short)f2bf(v0.x); a[1] = (short)f2bf(v0.y);
                a[2] = (short)f2bf(v0.z); a[3] = (short)f2bf(v0.w);
                a[4] = (short)f2bf(v1.x); a[5] = (short)f2bf(v1.y);
                a[6] = (short)f2bf(v1.z); a[7] = (short)f2bf(v1.w);
            } else {
                a = *(const s16x8*)(xb + xrow * HID + ks * 32 + q * 8);
            }
            const int kb = 128 + ks * 32 + q * 8;
#pragma unroll
            for (int nt = 0; nt < 8; nt++) {
                s16x8 b = *(const s16x8*)&WT[wt_idx(nt * 16 + l16, kb)];
                acc[nt] = __builtin_amdgcn_mfma_f32_16x16x32_bf16(a, b, acc[nt], 0, 0, 0);
            }
        }
        // epilogue. D layout (m89-verified): col = lane&15, row = (lane>>4)*4 + i
#pragma unroll
        for (int nt = 0; nt < 8; nt++) {
            const int n = nt * 16 + l16;
            const float bv = bl[n];
#pragma unroll
            for (int i = 0; i < 4; i++) {
                float v = acc[nt][i] + bv;
                out[(size_t)(base + q * 4 + i) * HID + n] = f2bf(fmaxf(v, 0.0f));
            }
        }
    }
}

// ---------------- linear head: z = x @ w + b   ([N,128]@[128,64], x bf16, w/b f32, z bf16) ------
__global__ __launch_bounds__(256) void proj_kernel(
    int n_nodes, const unsigned short* __restrict__ x,
    const float* __restrict__ w, const float* __restrict__ bias, unsigned short* __restrict__ z)
{
    const int lane = threadIdx.x & 63, wid = threadIdx.x >> 6;
    const int l16 = lane & 15, q = lane >> 4;
    s16x8 bfr[4][4];
#pragma unroll
    for (int ks = 0; ks < 4; ks++)
#pragma unroll
        for (int nt = 0; nt < 4; nt++)
#pragma unroll
            for (int i = 0; i < 8; i++)
                bfr[ks][nt][i] = (short)f2bf(w[(ks * 32 + q * 8 + i) * OUTD + nt * 16 + l16]);
    const int n_tiles = n_nodes >> 4;
    const int stride = gridDim.x * 4;
    for (int tile = blockIdx.x * 4 + wid; tile < n_tiles; tile += stride) {
        const int base = tile << 4;
        const size_t mrow = (size_t)(base + l16);
        f32x4 acc[4] = {};
#pragma unroll
        for (int ks = 0; ks < 4; ks++) {
            s16x8 a = *(const s16x8*)(x + mrow * HID + ks * 32 + q * 8);
#pragma unroll
            for (int nt = 0; nt < 4; nt++)
                acc[nt] = __builtin_amdgcn_mfma_f32_16x16x32_bf16(a, bfr[ks][nt], acc[nt], 0, 0, 0);
        }
#pragma unroll
        for (int nt = 0; nt < 4; nt++) {
            const int n = nt * 16 + l16;
            const float bv = bias[n];
#pragma unroll
            for (int i = 0; i < 4; i++)
                z[(size_t)(base + q * 4 + i) * OUTD + n] = f2bf(acc[nt][i] + bv);
        }
    }
}

// ---------------- edge decoder: out[e] = relu([zs[r]|zt[c]] @ d1 + b1) @ d2 + b2 (out f32) ------
__global__ __launch_bounds__(256) void dec_kernel(
    const int* __restrict__ erow, const int* __restrict__ ecol,
    const unsigned short* __restrict__ zs, const unsigned short* __restrict__ zt,
    const float* __restrict__ w1, const float* __restrict__ b1,
    const float* __restrict__ w2, const float* __restrict__ b2,
    float* __restrict__ out)
{
    const int lane = threadIdx.x & 63, wid = threadIdx.x >> 6;
    const int l16 = lane & 15, q = lane >> 4;
    s16x8 bfr[4][4];  // d1_w [128][64] as B-fragments
#pragma unroll
    for (int ks = 0; ks < 4; ks++)
#pragma unroll
        for (int nt = 0; nt < 4; nt++)
#pragma unroll
            for (int i = 0; i < 8; i++)
                bfr[ks][nt][i] = (short)f2bf(w1[(ks * 32 + q * 8 + i) * OUTD + nt * 16 + l16]);
    float b1v[4], w2v[4];
#pragma unroll
    for (int nt = 0; nt < 4; nt++) {
        b1v[nt] = b1[nt * 16 + l16];
        w2v[nt] = w2[nt * 16 + l16];
    }
    const float b2v = b2[0];
    const int n_tiles = E_LBL >> 4;
    for (int tile = blockIdx.x * 4 + wid; tile < n_tiles; tile += gridDim.x * 4) {
        const int em = tile * 16 + l16;
        const size_t r = (size_t)erow[em], c = (size_t)ecol[em];
        f32x4 acc[4] = {};
        s16x8 a0 = *(const s16x8*)(zs + r * OUTD + q * 8);        // k 0..31
        s16x8 a1 = *(const s16x8*)(zs + r * OUTD + 32 + q * 8);   // k 32..63
        s16x8 a2 = *(const s16x8*)(zt + c * OUTD + q * 8);        // k 64..95
        s16x8 a3 = *(const s16x8*)(zt + c * OUTD + 32 + q * 8);   // k 96..127
#pragma unroll
        for (int nt = 0; nt < 4; nt++) {
            acc[nt] = __builtin_amdgcn_mfma_f32_16x16x32_bf16(a0, bfr[0][nt], acc[nt], 0, 0, 0);
            acc[nt] = __builtin_amdgcn_mfma_f32_16x16x32_bf16(a1, bfr[1][nt], acc[nt], 0, 0, 0);
            acc[nt] = __builtin_amdgcn_mfma_f32_16x16x32_bf16(a2, bfr[2][nt], acc[nt], 0, 0, 0);
            acc[nt] = __builtin_amdgcn_mfma_f32_16x16x32_bf16(a3, bfr[3][nt], acc[nt], 0, 0, 0);
        }
        float s[4] = {0.0f, 0.0f, 0.0f, 0.0f};
#pragma unroll
        for (int nt = 0; nt < 4; nt++)
#pragma unroll
            for (int i = 0; i < 4; i++)
                s[i] += fmaxf(acc[nt][i] + b1v[nt], 0.0f) * w2v[nt];
        // sum over the 16 lanes (n dim) of each quad-group
#pragma unroll
        for (int off = 8; off >= 1; off >>= 1)
#pragma unroll
            for (int i = 0; i < 4; i++)
                s[i] += __shfl_down(s[i], off, 16);
        if (l16 == 0) {
#pragma unroll
            for (int i = 0; i < 4; i++)
                out[tile * 16 + q * 4 + i] = s[i] + b2v;
        }
    }
}

extern "C" void kernel_launch(void* const* d_in, const int* in_sizes, int n_in,
                              void* d_out, int out_size, void* d_ws, size_t ws_size,
                              hipStream_t stream) {
    (void)in_sizes; (void)n_in; (void)out_size; (void)ws_size;
    const int* sotu_ids  = (const int*)d_in[0];
    const int* taxon_ids = (const int*)d_in[1];
    const int* ett_src   = (const int*)d_in[2];
    const int* ett_dst   = (const int*)d_in[3];
    const int* ets_src   = (const int*)d_in[4];
    const int* ets_dst   = (const int*)d_in[5];
    const int* elbl_row  = (const int*)d_in[6];
    const int* elbl_col  = (const int*)d_in[7];
    const float* sotu_emb  = (const float*)d_in[8];
    const float* taxon_emb = (const float*)d_in[9];
    const float* s1_wl = (const float*)d_in[10]; const float* s1_bl = (const float*)d_in[11]; const float* s1_wr = (const float*)d_in[12];
    const float* s2_wl = (const float*)d_in[13]; const float* s2_bl = (const float*)d_in[14]; const float* s2_wr = (const float*)d_in[15];
    const float* s3_wl = (const float*)d_in[16]; const float* s3_bl = (const float*)d_in[17]; const float* s3_wr = (const float*)d_in[18];
    const float* sl_w  = (const float*)d_in[19]; const float* sl_b  = (const float*)d_in[20];
    const float* t1_wl = (const float*)d_in[21]; const float* t1_bl = (const float*)d_in[22]; const float* t1_wr = (const float*)d_in[23];
    const float* t2_wl = (const float*)d_in[24]; const float* t2_bl = (const float*)d_in[25]; const float* t2_wr = (const float*)d_in[26];
    const float* tl_w  = (const float*)d_in[27]; const float* tl_b  = (const float*)d_in[28];
    const float* d1_w  = (const float*)d_in[29]; const float* d1_b  = (const float*)d_in[30];
    const float* d2_w  = (const float*)d_in[31]; const float* d2_b  = (const float*)d_in[32];
    float* out = (float*)d_out;

    // workspace (~387 MB). agg fp32 (max 250000 rows) reused by all aggregations; the sotu
    // aggregations run in two dst-halves. z_sotu aliases agg (dead after s3 half1).
    char* ws = (char*)d_ws;
    size_t off = 0;
    auto alloc = [&](size_t bytes) { void* p = ws + off; off = (off + bytes + 255) & ~(size_t)255; return p; };
    float* agg              = (float*)alloc((size_t)HALF_S * HID * 4);        // 128 MB
    float* deg_tt           = (float*)alloc((size_t)N_TAXON * 4);
    float* deg_ts           = (float*)alloc((size_t)N_SOTU * 4);
    unsigned short* taxon_x = (unsigned short*)alloc((size_t)N_TAXON * HID * 2);  // 51.2 MB
    unsigned short* tx1     = (unsigned short*)alloc((size_t)N_TAXON * HID * 2);  // 51.2 MB
    unsigned short* sotu_x  = (unsigned short*)alloc((size_t)N_SOTU * HID * 2);   // 128 MB
    unsigned short* z_taxon = (unsigned short*)alloc((size_t)N_TAXON * OUTD * 2); // 25.6 MB
    unsigned short* z_sotu  = (unsigned short*)agg;   // 64 MB, alias (agg dead by then)

    // degrees (ett shared by s1/t1/t2; ets by s2/s3)
    hipMemsetAsync(deg_tt, 0, (size_t)N_TAXON * 4, stream);
    hipMemsetAsync(deg_ts, 0, (size_t)N_SOTU * 4, stream);
    deg_kernel<<<(E_TT + 255) / 256, 256, 0, stream>>>(ett_dst, E_TT, deg_tt);
    deg_kernel<<<(E_TS + 255) / 256, 256, 0, stream>>>(ets_dst, E_TS, deg_ts);

    const int gTT = E_TT * 16 / 256, gTS = E_TS * 16 / 256;

    // A1 = mean_{ett} x_taxon  (shared by s1 and t1)
    hipMemsetAsync(agg, 0, (size_t)N_TAXON * HID * 4, stream);
    scatter_kernel<<<gTT, 256, 0, stream>>>(taxon_emb, nullptr, taxon_ids, ett_src, ett_dst, E_TT, 0, N_TAXON, agg);
    sage_kernel<<<512, 256, 0, stream>>>(N_TAXON, 0, agg, deg_tt, taxon_emb, nullptr, taxon_ids, s1_wl, s1_wr, s1_bl, taxon_x);
    sage_kernel<<<512, 256, 0, stream>>>(N_TAXON, 0, agg, deg_tt, taxon_emb, nullptr, taxon_ids, t1_wl, t1_wr, t1_bl, tx1);

    // taxon tail: T2 = mean_{ett} tx1 ; t2 (in-place) ; tl head
    hipMemsetAsync(agg, 0, (size_t)N_TAXON * HID * 4, stream);
    scatter_kernel<<<gTT, 256, 0, stream>>>(nullptr, tx1, nullptr, ett_src, ett_dst, E_TT, 0, N_TAXON, agg);
    sage_kernel<<<512, 256, 0, stream>>>(N_TAXON, 0, agg, deg_tt, nullptr, tx1, nullptr, t2_wl, t2_wr, t2_bl, tx1);
    proj_kernel<<<1024, 256, 0, stream>>>(N_TAXON, tx1, tl_w, tl_b, z_taxon);

    // s2: A2 = mean_{ets} x_taxon -> sotu, two dst-halves
    for (int h = 0; h < 2; ++h) {
        int lo = h * HALF_S;
        hipMemsetAsync(agg, 0, (size_t)HALF_S * HID * 4, stream);
        scatter_kernel<<<gTS, 256, 0, stream>>>(taxon_emb, nullptr, taxon_ids, ets_src, ets_dst, E_TS, lo, lo + HALF_S, agg);
        sage_kernel<<<512, 256, 0, stream>>>(HALF_S, lo, agg, deg_ts + lo, sotu_emb, nullptr, sotu_ids + lo,
                                             s2_wl, s2_wr, s2_bl, sotu_x + (size_t)lo * HID);
    }
    // s3: A3 = mean_{ets} taxon_x -> sotu, two dst-halves (in-place on sotu_x)
    for (int h = 0; h < 2; ++h) {
        int lo = h * HALF_S;
        hipMemsetAsync(agg, 0, (size_t)HALF_S * HID * 4, stream);
        scatter_kernel<<<gTS, 256, 0, stream>>>(nullptr, taxon_x, nullptr, ets_src, ets_dst, E_TS, lo, lo + HALF_S, agg);
        sage_kernel<<<512, 256, 0, stream>>>(HALF_S, lo, agg, deg_ts + lo, nullptr, sotu_x, nullptr,
                                             s3_wl, s3_wr, s3_bl, sotu_x + (size_t)lo * HID);
    }
    // sl head (agg now dead -> z_sotu lives there)
    proj_kernel<<<1024, 256, 0, stream>>>(N_SOTU, sotu_x, sl_w, sl_b, z_sotu);

    // edge decoder
    dec_kernel<<<1024, 256, 0, stream>>>(elbl_row, elbl_col, z_sotu, z_taxon, d1_w, d1_b, d2_w, d2_b, out);
}

// Round 3
// 1625.145 us; speedup vs baseline: 6.0998x; 6.0998x over previous
//
#include <hip/hip_runtime.h>

#define HID 128
#define OUTD 64
#define N_SOTU 500000
#define N_TAXON 200000
#define E_TT 200000
#define E_TS 1000000
#define E_LBL 500000
#define HALF_S 250000
#define SCAN_TILE 2048   // elements per scan block (256 thr x 8)

typedef short s16x8 __attribute__((ext_vector_type(8)));   // 8 bf16 (4 VGPRs) MFMA frag
typedef float f32x4 __attribute__((ext_vector_type(4)));

__device__ __forceinline__ unsigned short f2bf(float f) {  // f32 -> bf16 bits, RNE
    unsigned u = __builtin_bit_cast(unsigned, f);
    u += 0x7FFFu + ((u >> 16) & 1u);
    return (unsigned short)(u >> 16);
}
__device__ __forceinline__ float bf2f(unsigned short h) {
    unsigned u = ((unsigned)h) << 16;
    return __builtin_bit_cast(float, u);
}

// =================== CSR build: hist -> scan (3 kernels) -> fill ===================
__global__ void hist_kernel(const int* __restrict__ dst, int n, int* __restrict__ rp) {
    int e = blockIdx.x * 256 + threadIdx.x;
    if (e < n) atomicAdd(&rp[dst[e]], 1);
}

// in-place inclusive scan within SCAN_TILE blocks; bsums[b] = block total
__global__ __launch_bounds__(256) void scan1_kernel(int* __restrict__ a, int n, int* __restrict__ bsums) {
    __shared__ int tsum[256];
    const int t = threadIdx.x;
    const int base = blockIdx.x * SCAN_TILE + t * 8;
    int v[8]; int s = 0;
#pragma unroll
    for (int i = 0; i < 8; i++) {
        int x = (base + i < n) ? a[base + i] : 0;
        s += x; v[i] = s;                       // thread-local inclusive
    }
    tsum[t] = s;
    __syncthreads();
    for (int off = 1; off < 256; off <<= 1) {   // Hillis-Steele inclusive over 256
        int x = (t >= off) ? tsum[t - off] : 0;
        __syncthreads();
        tsum[t] += x;
        __syncthreads();
    }
    const int prev = (t > 0) ? tsum[t - 1] : 0;
#pragma unroll
    for (int i = 0; i < 8; i++)
        if (base + i < n) a[base + i] = v[i] + prev;
    if (t == 255) bsums[blockIdx.x] = tsum[255];
}

// single-block inclusive scan of bsums (nb <= 256)
__global__ __launch_bounds__(256) void scan2_kernel(int* __restrict__ bsums, int nb) {
    __shared__ int tsum[256];
    const int t = threadIdx.x;
    tsum[t] = (t < nb) ? bsums[t] : 0;
    __syncthreads();
    for (int off = 1; off < 256; off <<= 1) {
        int x = (t >= off) ? tsum[t - off] : 0;
        __syncthreads();
        tsum[t] += x;
        __syncthreads();
    }
    if (t < nb) bsums[t] = tsum[t];
}

__global__ __launch_bounds__(256) void scan3_kernel(int* __restrict__ a, int n, const int* __restrict__ bsums) {
    const int b = blockIdx.x;
    if (b == 0) return;
    const int add = bsums[b - 1];
    const int base = b * SCAN_TILE + threadIdx.x * 8;
#pragma unroll
    for (int i = 0; i < 8; i++)
        if (base + i < n) a[base + i] += add;
}

// fill buckets back-to-front; afterwards rp[d] = bucket start
__global__ void fill_kernel(const int* __restrict__ src, const int* __restrict__ dst, int n,
                            int* __restrict__ rp, int* __restrict__ sl) {
    int e = blockIdx.x * 256 + threadIdx.x;
    if (e < n) {
        int pos = atomicSub(&rp[dst[e]], 1) - 1;
        sl[pos] = src[e];
    }
}

// =================== gather mean: agg_bf16[d-lo] = mean_{j in bucket d} x[sl[j]] ==============
// 16 lanes per dst row, 8 feats/lane. Source f32 (xf, optional xids) or bf16 (xb).
__global__ __launch_bounds__(256) void gather_kernel(
    const float* __restrict__ xf, const unsigned short* __restrict__ xb,
    const int* __restrict__ xids,
    const int* __restrict__ rp, const int* __restrict__ sl,
    int n_dst_total, int n_edges, int lo, int rows,
    unsigned short* __restrict__ agg)
{
    const int g = blockIdx.x * 16 + (threadIdx.x >> 4);
    if (g >= rows) return;
    const int d = lo + g;
    const int l = threadIdx.x & 15;
    const int start = rp[d];
    const int end = (d + 1 < n_dst_total) ? rp[d + 1] : n_edges;
    float acc[8] = {0.f, 0.f, 0.f, 0.f, 0.f, 0.f, 0.f, 0.f};
    for (int j = start; j < end; ++j) {
        int s = sl[j];
        if (xids) s = xids[s];
        if (xf) {
            const float* p = xf + (size_t)s * HID + l * 8;
            float4 v0 = *(const float4*)p;
            float4 v1 = *(const float4*)(p + 4);
            acc[0] += v0.x; acc[1] += v0.y; acc[2] += v0.z; acc[3] += v0.w;
            acc[4] += v1.x; acc[5] += v1.y; acc[6] += v1.z; acc[7] += v1.w;
        } else {
            s16x8 b = *(const s16x8*)(xb + (size_t)s * HID + l * 8);
#pragma unroll
            for (int i = 0; i < 8; i++) acc[i] += bf2f((unsigned short)b[i]);
        }
    }
    const float inv = (end > start) ? 1.0f / (float)(end - start) : 0.0f;
    s16x8 o;
#pragma unroll
    for (int i = 0; i < 8; i++) o[i] = (short)f2bf(acc[i] * inv);
    *(s16x8*)(agg + (size_t)g * HID + l * 8) = o;
}

// =================== fused SAGE: out = relu( agg@wl + x@wr + bl ) ===================
// MFMA 16x16x32 bf16, K=256 (concat [agg | x]), N=128. Weights bf16 in LDS, transposed +
// XOR-granule-swizzled.
__device__ __forceinline__ int wt_idx(int n, int k) {
    return n * 256 + ((((k >> 3) ^ n) & 31) << 3) + (k & 7);
}

__global__ __launch_bounds__(256) void sage_kernel(
    int n_rows, int row0,
    const unsigned short* __restrict__ agg,   // bf16 mean, local rows [0, n_rows)
    const float* __restrict__ xf, const unsigned short* __restrict__ xb,  // one non-null
    const int* __restrict__ xids,    // pre-offset by row0; if null, xrow = row0 + local
    const float* __restrict__ wl, const float* __restrict__ wr,
    const float* __restrict__ bl,
    unsigned short* __restrict__ out)  // pre-offset by row0*HID
{
    __shared__ __align__(16) unsigned short WT[128 * 256];  // 64 KB: WT[n][k], k<128 wl, k>=128 wr
    for (int idx = threadIdx.x; idx < 128 * 128; idx += 256) {
        int n = idx & 127, k = idx >> 7;
        WT[wt_idx(n, k)]       = f2bf(wl[idx]);   // wl[k][n]
        WT[wt_idx(n, k + 128)] = f2bf(wr[idx]);   // wr[k][n]
    }
    __syncthreads();
    const int lane = threadIdx.x & 63, wid = threadIdx.x >> 6;
    const int l16 = lane & 15, q = lane >> 4;
    const int n_tiles = n_rows >> 4;
    const int stride = gridDim.x * 4;
    for (int tile = blockIdx.x * 4 + wid; tile < n_tiles; tile += stride) {
        const int base = tile << 4;
        const int lrow = base + l16;     // A-operand row (local) this lane feeds
        const size_t xrow = xids ? (size_t)xids[lrow] : (size_t)(row0 + lrow);
        f32x4 acc[8] = {};
        // K = 0..127 : aggregation (bf16 direct)
#pragma unroll
        for (int ks = 0; ks < 4; ks++) {
            s16x8 a = *(const s16x8*)(agg + (size_t)lrow * HID + ks * 32 + q * 8);
            const int kb = ks * 32 + q * 8;
#pragma unroll
            for (int nt = 0; nt < 8; nt++) {
                s16x8 b = *(const s16x8*)&WT[wt_idx(nt * 16 + l16, kb)];
                acc[nt] = __builtin_amdgcn_mfma_f32_16x16x32_bf16(a, b, acc[nt], 0, 0, 0);
            }
        }
        // K = 128..255 : x_dst
#pragma unroll
        for (int ks = 0; ks < 4; ks++) {
            s16x8 a;
            if (xf) {
                const float* xp = xf + xrow * HID + ks * 32 + q * 8;
                float4 v0 = *(const float4*)xp;
                float4 v1 = *(const float4*)(xp + 4);
                a[0] = (short)f2bf(v0.x); a[1] = (short)f2bf(v0.y);
                a[2] = (short)f2bf(v0.z); a[3] = (short)f2bf(v0.w);
                a[4] = (short)f2bf(v1.x); a[5] = (short)f2bf(v1.y);
                a[6] = (short)f2bf(v1.z); a[7] = (short)f2bf(v1.w);
            } else {
                a = *(const s16x8*)(xb + xrow * HID + ks * 32 + q * 8);
            }
            const int kb = 128 + ks * 32 + q * 8;
#pragma unroll
            for (int nt = 0; nt < 8; nt++) {
                s16x8 b = *(const s16x8*)&WT[wt_idx(nt * 16 + l16, kb)];
                acc[nt] = __builtin_amdgcn_mfma_f32_16x16x32_bf16(a, b, acc[nt], 0, 0, 0);
            }
        }
        // epilogue. D layout (m89-verified): col = lane&15, row = (lane>>4)*4 + i
#pragma unroll
        for (int nt = 0; nt < 8; nt++) {
            const int n = nt * 16 + l16;
            const float bv = bl[n];
#pragma unroll
            for (int i = 0; i < 4; i++) {
                float v = acc[nt][i] + bv;
                out[(size_t)(base + q * 4 + i) * HID + n] = f2bf(fmaxf(v, 0.0f));
            }
        }
    }
}

// =================== linear head: z = x @ w + b  ([N,128]@[128,64]) ===================
__global__ __launch_bounds__(256) void proj_kernel(
    int n_nodes, const unsigned short* __restrict__ x,
    const float* __restrict__ w, const float* __restrict__ bias, unsigned short* __restrict__ z)
{
    const int lane = threadIdx.x & 63, wid = threadIdx.x >> 6;
    const int l16 = lane & 15, q = lane >> 4;
    s16x8 bfr[4][4];
#pragma unroll
    for (int ks = 0; ks < 4; ks++)
#pragma unroll
        for (int nt = 0; nt < 4; nt++)
#pragma unroll
            for (int i = 0; i < 8; i++)
                bfr[ks][nt][i] = (short)f2bf(w[(ks * 32 + q * 8 + i) * OUTD + nt * 16 + l16]);
    const int n_tiles = n_nodes >> 4;
    const int stride = gridDim.x * 4;
    for (int tile = blockIdx.x * 4 + wid; tile < n_tiles; tile += stride) {
        const int base = tile << 4;
        const size_t mrow = (size_t)(base + l16);
        f32x4 acc[4] = {};
#pragma unroll
        for (int ks = 0; ks < 4; ks++) {
            s16x8 a = *(const s16x8*)(x + mrow * HID + ks * 32 + q * 8);
#pragma unroll
            for (int nt = 0; nt < 4; nt++)
                acc[nt] = __builtin_amdgcn_mfma_f32_16x16x32_bf16(a, bfr[ks][nt], acc[nt], 0, 0, 0);
        }
#pragma unroll
        for (int nt = 0; nt < 4; nt++) {
            const int n = nt * 16 + l16;
            const float bv = bias[n];
#pragma unroll
            for (int i = 0; i < 4; i++)
                z[(size_t)(base + q * 4 + i) * OUTD + n] = f2bf(acc[nt][i] + bv);
        }
    }
}

// =================== edge decoder ===================
__global__ __launch_bounds__(256) void dec_kernel(
    const int* __restrict__ erow, const int* __restrict__ ecol,
    const unsigned short* __restrict__ zs, const unsigned short* __restrict__ zt,
    const float* __restrict__ w1, const float* __restrict__ b1,
    const float* __restrict__ w2, const float* __restrict__ b2,
    float* __restrict__ out)
{
    const int lane = threadIdx.x & 63, wid = threadIdx.x >> 6;
    const int l16 = lane & 15, q = lane >> 4;
    s16x8 bfr[4][4];  // d1_w [128][64] as B-fragments
#pragma unroll
    for (int ks = 0; ks < 4; ks++)
#pragma unroll
        for (int nt = 0; nt < 4; nt++)
#pragma unroll
            for (int i = 0; i < 8; i++)
                bfr[ks][nt][i] = (short)f2bf(w1[(ks * 32 + q * 8 + i) * OUTD + nt * 16 + l16]);
    float b1v[4], w2v[4];
#pragma unroll
    for (int nt = 0; nt < 4; nt++) {
        b1v[nt] = b1[nt * 16 + l16];
        w2v[nt] = w2[nt * 16 + l16];
    }
    const float b2v = b2[0];
    const int n_tiles = E_LBL >> 4;
    for (int tile = blockIdx.x * 4 + wid; tile < n_tiles; tile += gridDim.x * 4) {
        const int em = tile * 16 + l16;
        const size_t r = (size_t)erow[em], c = (size_t)ecol[em];
        f32x4 acc[4] = {};
        s16x8 a0 = *(const s16x8*)(zs + r * OUTD + q * 8);
        s16x8 a1 = *(const s16x8*)(zs + r * OUTD + 32 + q * 8);
        s16x8 a2 = *(const s16x8*)(zt + c * OUTD + q * 8);
        s16x8 a3 = *(const s16x8*)(zt + c * OUTD + 32 + q * 8);
#pragma unroll
        for (int nt = 0; nt < 4; nt++) {
            acc[nt] = __builtin_amdgcn_mfma_f32_16x16x32_bf16(a0, bfr[0][nt], acc[nt], 0, 0, 0);
            acc[nt] = __builtin_amdgcn_mfma_f32_16x16x32_bf16(a1, bfr[1][nt], acc[nt], 0, 0, 0);
            acc[nt] = __builtin_amdgcn_mfma_f32_16x16x32_bf16(a2, bfr[2][nt], acc[nt], 0, 0, 0);
            acc[nt] = __builtin_amdgcn_mfma_f32_16x16x32_bf16(a3, bfr[3][nt], acc[nt], 0, 0, 0);
        }
        float s[4] = {0.0f, 0.0f, 0.0f, 0.0f};
#pragma unroll
        for (int nt = 0; nt < 4; nt++)
#pragma unroll
            for (int i = 0; i < 4; i++)
                s[i] += fmaxf(acc[nt][i] + b1v[nt], 0.0f) * w2v[nt];
#pragma unroll
        for (int off = 8; off >= 1; off >>= 1)
#pragma unroll
            for (int i = 0; i < 4; i++)
                s[i] += __shfl_down(s[i], off, 16);
        if (l16 == 0) {
#pragma unroll
            for (int i = 0; i < 4; i++)
                out[tile * 16 + q * 4 + i] = s[i] + b2v;
        }
    }
}

// =================== host side ===================
static void build_csr(const int* src, const int* dst, int n_edges, int n_dst,
                      int* rp, int* sl, int* bsums, hipStream_t stream) {
    hipMemsetAsync(rp, 0, (size_t)n_dst * 4, stream);
    hist_kernel<<<(n_edges + 255) / 256, 256, 0, stream>>>(dst, n_edges, rp);
    const int nb = (n_dst + SCAN_TILE - 1) / SCAN_TILE;   // <= 245, fits scan2's 256
    scan1_kernel<<<nb, 256, 0, stream>>>(rp, n_dst, bsums);
    scan2_kernel<<<1, 256, 0, stream>>>(bsums, nb);
    scan3_kernel<<<nb, 256, 0, stream>>>(rp, n_dst, bsums);
    fill_kernel<<<(n_edges + 255) / 256, 256, 0, stream>>>(src, dst, n_edges, rp, sl);
}

extern "C" void kernel_launch(void* const* d_in, const int* in_sizes, int n_in,
                              void* d_out, int out_size, void* d_ws, size_t ws_size,
                              hipStream_t stream) {
    (void)in_sizes; (void)n_in; (void)out_size; (void)ws_size;
    const int* sotu_ids  = (const int*)d_in[0];
    const int* taxon_ids = (const int*)d_in[1];
    const int* ett_src   = (const int*)d_in[2];
    const int* ett_dst   = (const int*)d_in[3];
    const int* ets_src   = (const int*)d_in[4];
    const int* ets_dst   = (const int*)d_in[5];
    const int* elbl_row  = (const int*)d_in[6];
    const int* elbl_col  = (const int*)d_in[7];
    const float* sotu_emb  = (const float*)d_in[8];
    const float* taxon_emb = (const float*)d_in[9];
    const float* s1_wl = (const float*)d_in[10]; const float* s1_bl = (const float*)d_in[11]; const float* s1_wr = (const float*)d_in[12];
    const float* s2_wl = (const float*)d_in[13]; const float* s2_bl = (const float*)d_in[14]; const float* s2_wr = (const float*)d_in[15];
    const float* s3_wl = (const float*)d_in[16]; const float* s3_bl = (const float*)d_in[17]; const float* s3_wr = (const float*)d_in[18];
    const float* sl_w  = (const float*)d_in[19]; const float* sl_b  = (const float*)d_in[20];
    const float* t1_wl = (const float*)d_in[21]; const float* t1_bl = (const float*)d_in[22]; const float* t1_wr = (const float*)d_in[23];
    const float* t2_wl = (const float*)d_in[24]; const float* t2_bl = (const float*)d_in[25]; const float* t2_wr = (const float*)d_in[26];
    const float* tl_w  = (const float*)d_in[27]; const float* tl_b  = (const float*)d_in[28];
    const float* d1_w  = (const float*)d_in[29]; const float* d1_b  = (const float*)d_in[30];
    const float* d2_w  = (const float*)d_in[31]; const float* d2_b  = (const float*)d_in[32];
    float* out = (float*)d_out;

    // workspace (~328 MB)
    char* ws = (char*)d_ws;
    size_t off = 0;
    auto alloc = [&](size_t bytes) { void* p = ws + off; off = (off + bytes + 255) & ~(size_t)255; return p; };
    unsigned short* agg     = (unsigned short*)alloc((size_t)HALF_S * HID * 2);   // 64 MB (bf16 mean)
    unsigned short* taxon_x = (unsigned short*)alloc((size_t)N_TAXON * HID * 2);  // 51.2 MB
    unsigned short* tx1     = (unsigned short*)alloc((size_t)N_TAXON * HID * 2);  // 51.2 MB
    unsigned short* sotu_x  = (unsigned short*)alloc((size_t)N_SOTU * HID * 2);   // 128 MB
    unsigned short* z_taxon = (unsigned short*)alloc((size_t)N_TAXON * OUTD * 2); // 25.6 MB
    int* rp_ts = (int*)alloc((size_t)N_SOTU * 4);    // 2 MB
    int* sl_ts = (int*)alloc((size_t)E_TS * 4);      // 4 MB
    int* rp_tt = (int*)alloc((size_t)N_TAXON * 4);   // 0.8 MB
    int* sl_tt = (int*)alloc((size_t)E_TT * 4);      // 0.8 MB
    int* bsums = (int*)alloc(256 * 4);
    unsigned short* z_sotu = agg;   // 64 MB alias; agg dead after last s3 sage

    // CSR builds (tt used by A1 and T2; ts by A2 and A3)
    build_csr(ett_src, ett_dst, E_TT, N_TAXON, rp_tt, sl_tt, bsums, stream);
    build_csr(ets_src, ets_dst, E_TS, N_SOTU, rp_ts, sl_ts, bsums, stream);

    // A1 = mean_{ett} x_taxon (shared by s1/t1)
    gather_kernel<<<(N_TAXON + 15) / 16, 256, 0, stream>>>(
        taxon_emb, nullptr, taxon_ids, rp_tt, sl_tt, N_TAXON, E_TT, 0, N_TAXON, agg);
    sage_kernel<<<512, 256, 0, stream>>>(N_TAXON, 0, agg, taxon_emb, nullptr, taxon_ids,
                                         s1_wl, s1_wr, s1_bl, taxon_x);
    sage_kernel<<<512, 256, 0, stream>>>(N_TAXON, 0, agg, taxon_emb, nullptr, taxon_ids,
                                         t1_wl, t1_wr, t1_bl, tx1);

    // taxon tail: T2 = mean_{ett} tx1 ; t2 (in-place) ; tl head
    gather_kernel<<<(N_TAXON + 15) / 16, 256, 0, stream>>>(
        nullptr, tx1, nullptr, rp_tt, sl_tt, N_TAXON, E_TT, 0, N_TAXON, agg);
    sage_kernel<<<512, 256, 0, stream>>>(N_TAXON, 0, agg, nullptr, tx1, nullptr,
                                         t2_wl, t2_wr, t2_bl, tx1);
    proj_kernel<<<1024, 256, 0, stream>>>(N_TAXON, tx1, tl_w, tl_b, z_taxon);

    // s2: A2 = mean_{ets} x_taxon -> sotu (two dst-halves)
    for (int h = 0; h < 2; ++h) {
        int lo = h * HALF_S;
        gather_kernel<<<(HALF_S + 15) / 16, 256, 0, stream>>>(
            taxon_emb, nullptr, taxon_ids, rp_ts, sl_ts, N_SOTU, E_TS, lo, HALF_S, agg);
        sage_kernel<<<512, 256, 0, stream>>>(HALF_S, lo, agg, sotu_emb, nullptr, sotu_ids + lo,
                                             s2_wl, s2_wr, s2_bl, sotu_x + (size_t)lo * HID);
    }
    // s3: A3 = mean_{ets} taxon_x -> sotu (two dst-halves, in-place on sotu_x)
    for (int h = 0; h < 2; ++h) {
        int lo = h * HALF_S;
        gather_kernel<<<(HALF_S + 15) / 16, 256, 0, stream>>>(
            nullptr, taxon_x, nullptr, rp_ts, sl_ts, N_SOTU, E_TS, lo, HALF_S, agg);
        sage_kernel<<<512, 256, 0, stream>>>(HALF_S, lo, agg, nullptr, sotu_x, nullptr,
                                             s3_wl, s3_wr, s3_bl, sotu_x + (size_t)lo * HID);
    }
    // sl head (agg dead -> z_sotu lives there)
    proj_kernel<<<1024, 256, 0, stream>>>(N_SOTU, sotu_x, sl_w, sl_b, z_sotu);

    // edge decoder
    dec_kernel<<<1024, 256, 0, stream>>>(elbl_row, elbl_col, z_sotu, z_taxon,
                                         d1_w, d1_b, d2_w, d2_b, out);
}